// Round 20
// baseline (674.000 us; speedup 1.0000x reference)
//
#include <hip/hip_runtime.h>
#include <hip/hip_bf16.h>

#define T_LEN 4096
#define H_DIM 2048
#define HKn 16
#define HVn 32
#define DKn 128
#define DVn 128
#define KEY_DIM 2048
#define VAL_DIM 4096

typedef unsigned int u32;
typedef unsigned short u16;
typedef __attribute__((ext_vector_type(8))) short bf16x8;
typedef __attribute__((ext_vector_type(4))) float f32x4;

__device__ __forceinline__ u16 f2bf(float x){
  u32 u = __float_as_uint(x);
  u32 r = (u + 0x7fffu + ((u>>16)&1u)) >> 16;
  return (u16)r;
}
__device__ __forceinline__ float bf2f(u32 b){ return __uint_as_float(b<<16); }
__device__ __forceinline__ u32 packbf(float a, float b){ return (u32)f2bf(a) | ((u32)f2bf(b)<<16); }

// ---------------- fp32 -> bf16 elementwise ----------------
__global__ __launch_bounds__(256) void k_cvt(const float* __restrict__ in, u16* __restrict__ out, int n){
  int i = (blockIdx.x*256 + threadIdx.x)*8;
  if (i >= n) return;
  float4 a = *(const float4*)(in+i);
  float4 b = *(const float4*)(in+i+4);
  uint4 o;
  o.x = packbf(a.x,a.y); o.y = packbf(a.z,a.w);
  o.z = packbf(b.x,b.y); o.w = packbf(b.z,b.w);
  *(uint4*)(out+i) = o;
}

// ---------------- fp32 [R][C] -> bf16 transposed [C][R] ----------------
__global__ __launch_bounds__(256) void k_tcvt(const float* __restrict__ in, u16* __restrict__ out, int R, int C){
  __shared__ float tile[32][33];
  int c0 = blockIdx.x*32, r0 = blockIdx.y*32;
  int tx = threadIdx.x & 31, ty = threadIdx.x >> 5;
#pragma unroll
  for (int i=0;i<4;++i) tile[ty+8*i][tx] = in[(size_t)(r0+ty+8*i)*C + c0+tx];
  __syncthreads();
#pragma unroll
  for (int i=0;i<4;++i) out[(size_t)(c0+ty+8*i)*R + r0+tx] = f2bf(tile[tx][ty+8*i]);
}

// ---------------- ba = X @ W_ba  ->  gT [HVn][T], bT [HVn][T] ----------------
__global__ __launch_bounds__(256) void k_ba(const float* __restrict__ X, const float* __restrict__ W,
    const float* __restrict__ A_log, const float* __restrict__ dt_bias,
    float* __restrict__ gT, float* __restrict__ bT){
  int tid = threadIdx.x;
  int t = blockIdx.x*4 + (tid>>6);
  int j = tid & 63;
  const float* xr = X + (size_t)t*H_DIM;
  float acc = 0.f;
  for (int k=0;k<H_DIM;k+=4){
    float4 xv = *(const float4*)(xr+k);
    acc += xv.x*W[(size_t)(k+0)*64 + j];
    acc += xv.y*W[(size_t)(k+1)*64 + j];
    acc += xv.z*W[(size_t)(k+2)*64 + j];
    acc += xv.w*W[(size_t)(k+3)*64 + j];
  }
  if (j < HVn) {
    bT[(size_t)j*T_LEN + t] = 1.f/(1.f+__expf(-acc));
  } else {
    int h = j - HVn;
    float x = acc + dt_bias[h];
    float sp = (x > 20.f) ? x : log1pf(__expf(x));
    gT[(size_t)h*T_LEN + t] = -__expf(A_log[h]) * sp;
  }
}

typedef const __attribute__((address_space(1))) u32* gas_t;
typedef __attribute__((address_space(3))) u32* las_t;
__device__ __forceinline__ void gld16(const void* g, void* l){
  __builtin_amdgcn_global_load_lds((gas_t)g, (las_t)l, 16, 0, 0);
}
__device__ __forceinline__ f32x4 mf(bf16x8 a, bf16x8 b, f32x4 c){
  return __builtin_amdgcn_mfma_f32_16x16x32_bf16(a,b,c,0,0,0);
}

// ================ 256^2-tile GEMM (GEMM1), tail-fixed (R18) ================
#define G2_LDS 131072
#define SWX(a) ((a) ^ ((((a)>>9)&1)<<5))

template<int WRITE_BF16>
__global__ __launch_bounds__(512) void k_g256(const u16* __restrict__ A, const u16* __restrict__ BT,
    void* __restrict__ C1, void* __restrict__ C2, int NS, int M, int N, int K){
  extern __shared__ char sm[];
  const int tid=threadIdx.x, lane=tid&63, wave=tid>>6;
  const int fr=lane&15, fq=lane>>4;
  const int wm=wave>>2, wn=wave&3;
  const int nbm = M>>8, nwg = nbm*(N>>8);
  const int cpx = nwg>>3;
  const int swz = ((int)blockIdx.x & 7)*cpx + ((int)blockIdx.x >> 3);  // nwg%8==0
  const int m0 = (swz % nbm) << 8, n0 = (swz / nbm) << 8;
  const int NK = K >> 5;

  f32x4 acc[8][4];
#pragma unroll
  for (int i=0;i<8;++i)
#pragma unroll
    for (int j=0;j<4;++j) acc[i][j] = (f32x4){0.f,0.f,0.f,0.f};

  auto stageA=[&](int kt){
    char* base = sm + (size_t)(kt&3)*32768;
#pragma unroll
    for (int ld=0; ld<2; ++ld){
      int p = ld*8192 + wave*1024 + lane*16;
      int a = SWX(p);
      gld16((const char*)A + ((size_t)(m0 + (a>>6))*K + kt*32)*2 + (a&63), base + p);
    }
  };
  auto stageB=[&](int kt){
    char* base = sm + (size_t)(kt&3)*32768 + 16384;
#pragma unroll
    for (int ld=0; ld<2; ++ld){
      int p = ld*8192 + wave*1024 + lane*16;
      int a = SWX(p);
      gld16((const char*)BT + ((size_t)(n0 + (a>>6))*K + kt*32)*2 + (a&63), base + p);
    }
  };

  stageA(0); stageB(0); stageA(1); stageB(1); stageA(2); stageB(2);
  __syncthreads();

  for (int kt=0; kt<NK; ++kt){
    const char* bufA = sm + (size_t)(kt&3)*32768;
    const char* bufB = bufA + 16384;
    const int ksn = (kt+3 < NK) ? kt+3 : kt+3-NK;
    bf16x8 bfr[4], afr[4];
#pragma unroll
    for (int j=0;j<4;++j){
      int a = (wn*64 + j*16 + fr)*64 + fq*16;
      bfr[j] = *(const bf16x8*)(bufB + SWX(a));
    }
#pragma unroll
    for (int i=0;i<4;++i){
      int a = (wm*128 + i*16 + fr)*64 + fq*16;
      afr[i] = *(const bf16x8*)(bufA + SWX(a));
    }
    {  // stageA into buffer (kt+3)&3 from source tile ksn
      char* base = sm + (size_t)((kt+3)&3)*32768;
#pragma unroll
      for (int ld=0; ld<2; ++ld){
        int p = ld*8192 + wave*1024 + lane*16;
        int a = SWX(p);
        gld16((const char*)A + ((size_t)(m0 + (a>>6))*K + ksn*32)*2 + (a&63), base + p);
      }
    }
    asm volatile("s_barrier" ::: "memory");
    __builtin_amdgcn_s_setprio(1);
#pragma unroll
    for (int i=0;i<4;++i)
#pragma unroll
      for (int j=0;j<4;++j) acc[i][j] = mf(afr[i], bfr[j], acc[i][j]);
    __builtin_amdgcn_s_setprio(0);
    asm volatile("s_barrier" ::: "memory");
#pragma unroll
    for (int i=0;i<4;++i){
      int a = (wm*128 + 64 + i*16 + fr)*64 + fq*16;
      afr[i] = *(const bf16x8*)(bufA + SWX(a));
    }
    {  // stageB into buffer (kt+3)&3 from source tile ksn
      char* base = sm + (size_t)((kt+3)&3)*32768 + 16384;
#pragma unroll
      for (int ld=0; ld<2; ++ld){
        int p = ld*8192 + wave*1024 + lane*16;
        int a = SWX(p);
        gld16((const char*)BT + ((size_t)(n0 + (a>>6))*K + ksn*32)*2 + (a&63), base + p);
      }
    }
    asm volatile("s_barrier" ::: "memory");
    __builtin_amdgcn_s_setprio(1);
#pragma unroll
    for (int i=0;i<4;++i)
#pragma unroll
      for (int j=0;j<4;++j) acc[4+i][j] = mf(afr[i], bfr[j], acc[4+i][j]);
    __builtin_amdgcn_s_setprio(0);
    asm volatile("s_waitcnt vmcnt(8)" ::: "memory");
    asm volatile("s_barrier" ::: "memory");
  }

  const int inc1 = (n0 < NS);
  const int ldc = inc1 ? NS : (N - NS);
  const int nb  = inc1 ? n0 : (n0 - NS);
  u16*   Cb16 = (u16*)(inc1 ? C1 : C2);
  float* Cbf  = (float*)(inc1 ? C1 : C2);
#pragma unroll
  for (int mt=0; mt<8; ++mt)
#pragma unroll
    for (int nt=0; nt<4; ++nt){
      int row = m0 + wm*128 + mt*16 + fq*4;
      int col = nb + wn*64 + nt*16 + fr;
#pragma unroll
      for (int r=0;r<4;++r){
        float v = acc[mt][nt][r];
        if (WRITE_BF16) Cb16[(size_t)(row+r)*ldc + col] = f2bf(v);
        else            Cbf [(size_t)(row+r)*ldc + col] = v;
      }
    }
}

// ================ 128x256-tile GEMM (GEMM2), tail-fixed (R18) ================
#define GW_LDS 98304
__global__ __launch_bounds__(512) void k_gw(const u16* __restrict__ A, const u16* __restrict__ BT,
    float* __restrict__ C, int M, int N, int K){
  extern __shared__ char sm[];
  const int tid=threadIdx.x, lane=tid&63, wave=tid>>6;
  const int fr=lane&15, fq=lane>>4;
  const int wm=wave>>2, wn=wave&3;
  const int nbm=M>>7, nwg=nbm*(N>>8);
  const int cpx=nwg>>3;
  const int swz=((int)blockIdx.x&7)*cpx + ((int)blockIdx.x>>3);   // nwg%8==0
  const int m0=(swz%nbm)<<7, n0=(swz/nbm)<<8;
  const int NK=K>>5;

  f32x4 acc[4][4];
#pragma unroll
  for(int i=0;i<4;++i)
#pragma unroll
    for(int j=0;j<4;++j) acc[i][j]=(f32x4){0.f,0.f,0.f,0.f};

  auto stage=[&](int kt, int buf){
    char* base = sm + (size_t)buf*24576;
    { int p=tid*16; int a=SWX(p);
      gld16((const char*)A + ((size_t)(m0+(a>>6))*K + kt*32)*2 + (a&63), base+p); }
    char* bb = base + 8192;
#pragma unroll
    for(int ld=0;ld<2;++ld){ int p=ld*8192+tid*16; int a=SWX(p);
      gld16((const char*)BT + ((size_t)(n0+(a>>6))*K + kt*32)*2 + (a&63), bb+p); }
  };
  stage(0,0); stage(1,1); stage(2,2);
  __syncthreads();

  for(int kt=0;kt<NK;++kt){
    const char* bufA = sm + (size_t)(kt&3)*24576;
    const char* bufB = bufA + 8192;
    bf16x8 afr[4], bfr[4];
#pragma unroll
    for(int i=0;i<4;++i){ int a=(wm*64+i*16+fr)*64+fq*16; afr[i]=*(const bf16x8*)(bufA+SWX(a)); }
#pragma unroll
    for(int j=0;j<4;++j){ int a=(wn*64+j*16+fr)*64+fq*16; bfr[j]=*(const bf16x8*)(bufB+SWX(a)); }
    { int ksn=(kt+3<NK)?kt+3:kt+3-NK; stage(ksn,(kt+3)&3); }
    asm volatile("s_barrier":::"memory");
    __builtin_amdgcn_s_setprio(1);
#pragma unroll
    for(int i=0;i<4;++i)
#pragma unroll
      for(int j=0;j<4;++j) acc[i][j]=mf(afr[i],bfr[j],acc[i][j]);
    __builtin_amdgcn_s_setprio(0);
    asm volatile("s_waitcnt vmcnt(6)":::"memory");
    asm volatile("s_barrier":::"memory");
  }

#pragma unroll
  for(int mt=0;mt<4;++mt)
#pragma unroll
    for(int nt=0;nt<4;++nt){
      int row=m0+wm*64+mt*16+fq*4;
      int col=n0+wn*64+nt*16+fr;
#pragma unroll
      for(int r=0;r<4;++r)
        C[(size_t)(row+r)*N + col] = acc[mt][nt][r];
    }
}

// ------- causal conv(KW=4)+SiLU+l2norm, one-pass rolling registers -------
__global__ __launch_bounds__(256) void k_conv(const u16* __restrict__ qkv, const float* __restrict__ cw,
    u16* __restrict__ qn, u16* __restrict__ kn, u16* __restrict__ vv){
  const int r = blockIdx.y;
  const int t0 = blockIdx.x*32;
  const int c = r*2048 + threadIdx.x*8;
  float wgt[8][4];
#pragma unroll
  for(int i=0;i<8;++i){
    float4 wv=*(const float4*)(cw+(size_t)(c+i)*4);
    wgt[i][0]=wv.x;wgt[i][1]=wv.y;wgt[i][2]=wv.z;wgt[i][3]=wv.w;
  }
  float h0[8],h1[8],h2[8];
  if(t0>=3){
    uint4 a=*(const uint4*)(qkv+(size_t)(t0-3)*8192+c);
    uint4 b=*(const uint4*)(qkv+(size_t)(t0-2)*8192+c);
    uint4 d=*(const uint4*)(qkv+(size_t)(t0-1)*8192+c);
    h0[0]=bf2f(a.x&0xffffu);h0[1]=bf2f(a.x>>16);h0[2]=bf2f(a.y&0xffffu);h0[3]=bf2f(a.y>>16);
    h0[4]=bf2f(a.z&0xffffu);h0[5]=bf2f(a.z>>16);h0[6]=bf2f(a.w&0xffffu);h0[7]=bf2f(a.w>>16);
    h1[0]=bf2f(b.x&0xffffu);h1[1]=bf2f(b.x>>16);h1[2]=bf2f(b.y&0xffffu);h1[3]=bf2f(b.y>>16);
    h1[4]=bf2f(b.z&0xffffu);h1[5]=bf2f(b.z>>16);h1[6]=bf2f(b.w&0xffffu);h1[7]=bf2f(b.w>>16);
    h2[0]=bf2f(d.x&0xffffu);h2[1]=bf2f(d.x>>16);h2[2]=bf2f(d.y&0xffffu);h2[3]=bf2f(d.y>>16);
    h2[4]=bf2f(d.z&0xffffu);h2[5]=bf2f(d.z>>16);h2[6]=bf2f(d.w&0xffffu);h2[7]=bf2f(d.w>>16);
  } else {
#pragma unroll
    for(int i=0;i<8;++i){h0[i]=0.f;h1[i]=0.f;h2[i]=0.f;}
  }
  uint4 c0=*(const uint4*)(qkv+(size_t)t0*8192+c);
  uint4 c1=*(const uint4*)(qkv+(size_t)(t0+1)*8192+c);
  uint4 c2=*(const uint4*)(qkv+(size_t)(t0+2)*8192+c);
  for(int it=0; it<32; ++it){
    int t=t0+it;
    uint4 cn = (t+3<T_LEN)? *(const uint4*)(qkv+(size_t)(t+3)*8192+c) : c0;
    float cur[8];
    cur[0]=bf2f(c0.x&0xffffu);cur[1]=bf2f(c0.x>>16);cur[2]=bf2f(c0.y&0xffffu);cur[3]=bf2f(c0.y>>16);
    cur[4]=bf2f(c0.z&0xffffu);cur[5]=bf2f(c0.z>>16);cur[6]=bf2f(c0.w&0xffffu);cur[7]=bf2f(c0.w>>16);
    float y[8];
#pragma unroll
    for(int i=0;i<8;++i)
      y[i]=fmaf(h0[i],wgt[i][0],fmaf(h1[i],wgt[i][1],fmaf(h2[i],wgt[i][2],cur[i]*wgt[i][3])));
#pragma unroll
    for(int i=0;i<8;++i) y[i]=y[i]/(1.f+__expf(-y[i]));
    if(r<=1){
      float ss=0.f;
#pragma unroll
      for(int i=0;i<8;++i) ss+=y[i]*y[i];
      ss+=__shfl_xor(ss,1);ss+=__shfl_xor(ss,2);ss+=__shfl_xor(ss,4);ss+=__shfl_xor(ss,8);
      float sc=1.f/sqrtf(ss+1e-6f);
      if(r==0) sc*=0.08838834764831845f;
#pragma unroll
      for(int i=0;i<8;++i) y[i]*=sc;
      u16* dst=(r==0?qn:kn)+(size_t)t*KEY_DIM+(c-r*2048);
      *(uint4*)dst=make_uint4(packbf(y[0],y[1]),packbf(y[2],y[3]),packbf(y[4],y[5]),packbf(y[6],y[7]));
    } else {
      u16* dst=vv+(size_t)t*VAL_DIM+(c-4096);
      *(uint4*)dst=make_uint4(packbf(y[0],y[1]),packbf(y[2],y[3]),packbf(y[4],y[5]),packbf(y[6],y[7]));
    }
#pragma unroll
    for(int i=0;i<8;++i){h0[i]=h1[i];h1[i]=h2[i];h2[i]=cur[i];}
    c0=c1;c1=c2;c2=cn;
  }
}

// ================ P1: per-chunk operator precompute (2 blocks/CU, swizzled outputs) ================
#define P1_K    0
#define P1_Q    16384
#define P1_DT   16384
#define P1_WMT  24576
#define P1_KT   32768
#define P1_NBP  49152
#define P1_AQ   57344
#define P1_NBD  65536
#define P1_TII  69632
#define P1_R1T  73728
#define P1_TAB  77824
#define P1_SIZE 78912

#define SW7(r,cb) ((cb) ^ (((r)&7)<<4))
#define SW3(r,cb) ((cb) ^ (((r)&3)<<4))
#define aK(r,cb)   (P1_K   + (r)*256 + SW7(r,cb))
#define aQ2(r,cb)  (P1_Q   + (r)*256 + SW7(r,cb))
#define aKT(d,cb)  (P1_KT  + (d)*128 + SW7(d,cb))
#define aNBP(t,cb) (P1_NBP + (t)*128 + SW7(t,cb))
#define aAQ(t,cb)  (P1_AQ  + (t)*128 + SW7(t,cb))
#define aDT(s,cb)  (P1_DT  + (s)*128 + SW7(s,cb))
#define aWMT(s,cb) (P1_WMT + (s)*128 + SW7(s,cb))
#define aTII(b,r,cb) (P1_TII + (b)*1024 + (r)*64 + SW3(r,cb))
#define aR1T(v,cb)   (P1_R1T + (v)*64 + SW3(v,cb))

__global__ __launch_bounds__(256) void k_prep(const u16* __restrict__ qn, const u16* __restrict__ kn,
    const float* __restrict__ gT, const float* __restrict__ bT,
    u16* __restrict__ aqmg, u16* __restrict__ kwmg, float* __restrict__ tabg){
  extern __shared__ char sm[];
  const int tid=threadIdx.x, lane=tid&63, wave=tid>>6;
  const int fr=lane&15, fq=lane>>4;
  const int b=blockIdx.x, h=b>>6, c=b&63, kh=h>>1;
  const f32x4 z4={0.f,0.f,0.f,0.f};
  for (int off=P1_NBD+tid*16; off<P1_TAB; off+=4096) *(uint4*)(sm+off)=make_uint4(0,0,0,0);
  {
    int srow = wave*4 + (lane>>4);
    int pb = (lane&15)*16;
#pragma unroll
    for (int r=0;r<4;++r){
      int row=r*16+srow;
      int gcb = pb ^ ((row&7)<<4);
      gld16((const char*)kn + ((size_t)((c<<6)+row)*KEY_DIM + kh*DKn)*2 + gcb, sm + P1_K + r*4096 + wave*1024);
      gld16((const char*)qn + ((size_t)((c<<6)+row)*KEY_DIM + kh*DKn)*2 + gcb, sm + P1_Q + r*4096 + wave*1024);
    }
  }
  float* TB=(float*)(sm+P1_TAB);
  if (wave==0){
    int t=lane;
    float gv=gT[(size_t)h*T_LEN+(c<<6)+t];
    float bv=bT[(size_t)h*T_LEN+(c<<6)+t];
    float s=gv;
    for(int o2=1;o2<64;o2<<=1){ float u=__shfl_up(s,o2,64); if(lane>=o2) s+=u; }
    float cgL=__shfl(s,63,64);
    float gam=__expf(s);
    TB[t]=s; TB[64+t]=gam; TB[128+t]=__expf(cgL-s); TB[192+t]=bv;
    float* tg=tabg+(size_t)b*192;
    tg[t]=gam; tg[64+t]=bv;
    if(t==0) tg[128]=__expf(cgL);
  }
  __syncthreads();
#pragma unroll
  for (int dd=0;dd<2;++dd){
    int tp=tid&31, d0=((tid>>5)+dd*8)*8;
    bf16x8 r0=*(const bf16x8*)(sm+aK(2*tp,d0*2));
    bf16x8 r1=*(const bf16x8*)(sm+aK(2*tp+1,d0*2));
#pragma unroll
    for(int j=0;j<8;++j){
      u32 pk=((u32)(u16)r0[j])|((u32)(u16)r1[j]<<16);
      *(u32*)(sm+aKT(d0+j,tp*4))=pk;
    }
  }
  const int ra=(wave>>1)*32, rb=(wave&1)*32;
  f32x4 kq[2][2], qk[2][2];
#pragma unroll
  for(int ta=0;ta<2;++ta)
#pragma unroll
  for(int tb=0;tb<2;++tb){ kq[ta][tb]=z4; qk[ta][tb]=z4; }
#pragma unroll
  for(int kk=0;kk<4;++kk){
    int cb=kk*64+fq*16;
    bf16x8 Ak0=*(const bf16x8*)(sm+aK(ra+fr,cb));
    bf16x8 Ak1=*(const bf16x8*)(sm+aK(ra+16+fr,cb));
    bf16x8 Aq0=*(const bf16x8*)(sm+aQ2(ra+fr,cb));
    bf16x8 Aq1=*(const bf16x8*)(sm+aQ2(ra+16+fr,cb));
    bf16x8 Bk0=*(const bf16x8*)(sm+aK(rb+fr,cb));
    bf16x8 Bk1=*(const bf16x8*)(sm+aK(rb+16+fr,cb));
    if(ra>=rb)      { kq[0][0]=mf(Ak0,Bk0,kq[0][0]); qk[0][0]=mf(Aq0,Bk0,qk[0][0]); }
    if(ra>=rb+16)   { kq[0][1]=mf(Ak0,Bk1,kq[0][1]); qk[0][1]=mf(Aq0,Bk1,qk[0][1]); }
    if(ra+16>=rb)   { kq[1][0]=mf(Ak1,Bk0,kq[1][0]); qk[1][0]=mf(Aq1,Bk0,qk[1][0]); }
    if(ra+16>=rb+16){ kq[1][1]=mf(Ak1,Bk1,kq[1][1]); qk[1][1]=mf(Aq1,Bk1,qk[1][1]); }
  }
  {
    const float* cg=TB; const float* Be=TB+192;
#pragma unroll
    for(int ta=0;ta<2;++ta)
#pragma unroll
    for(int tb=0;tb<2;++tb){
      int tab=ra+16*ta, tbb=rb+16*tb;
#pragma unroll
      for(int p=0;p<4;++p){
        int t=tab+fq*4+p, s2=tbb+fr;
        float e=__expf(cg[t]-cg[s2]);
        float nv=(s2<t)? -Be[t]*kq[ta][tb][p]*e : 0.f;
        *(u16*)(sm+aNBP(t,s2*2)) = (tbb<tab)? f2bf(nv):(u16)0;
        if(tbb==tab) ((float*)(sm+P1_NBD))[(tab>>4)*256+(fq*4+p)*16+fr]=nv;
        float av=(s2<=t)? qk[ta][tb][p]*e : 0.f;
        *(u16*)(sm+aAQ(t,s2*2)) = f2bf(av);
      }
    }
  }
  __syncthreads();   // C2: Q dead -> DT/WMT writable
  for (int off=P1_DT+tid*16; off<P1_DT+16384; off+=4096) *(uint4*)(sm+off)=make_uint4(0,0,0,0);
  {
    int r=lane&15;
    const float* nb=(const float*)(sm+P1_NBD)+wave*256+r*16;
    float n[16], t_[16];
#pragma unroll
    for(int j=0;j<16;++j){ n[j]=nb[j]; t_[j]=(j==r)?1.f:0.f; }
#pragma unroll
    for(int s=0;s<15;++s){
      float tsj[16];
#pragma unroll
      for(int j=0;j<16;++j)
        tsj[j]=__int_as_float(__builtin_amdgcn_ds_bpermute(s*4,__float_as_int(t_[j])));
      if(r>s){
#pragma unroll
        for(int j=0;j<16;++j) t_[j]=fmaf(n[s],tsj[j],t_[j]);
      }
    }
    if(lane<16){
      u32 pk[8];
#pragma unroll
      for(int j=0;j<8;++j) pk[j]=packbf(t_[2*j],t_[2*j+1]);
      *(uint4*)(sm+aTII(wave,r,0)) =make_uint4(pk[0],pk[1],pk[2],pk[3]);
      *(uint4*)(sm+aTII(wave,r,16))=make_uint4(pk[4],pk[5],pk[6],pk[7]);
    }
  }
  __syncthreads();   // D
  {
    const float* WV=TB+128;
    int vb=16*wave;
    for(int i=0;i<4;++i){
      f32x4 acc;
#pragma unroll
      for(int p=0;p<4;++p) acc[p]=(vb+fr==16*i+fq*4+p)?1.f:0.f;
      int np=(i+1)>>1;
      for(int jp=0;jp<np;++jp){
        bf16x8 A=*(const bf16x8*)(sm+aNBP(16*i+fr,jp*64+fq*16));
        bf16x8 B=*(const bf16x8*)(sm+aDT(vb+fr,jp*64+fq*16));
        acc=mf(A,B,acc);
      }
      uint2 w1; w1.x=packbf(acc[0],acc[1]); w1.y=packbf(acc[2],acc[3]);
      *(uint2*)(sm+aR1T(vb+fr,fq*8))=w1;
      bf16x8 At=*(const bf16x8*)(sm+aTII(i,fr,fq*16));
      bf16x8 Bt=*(const bf16x8*)(sm+aR1T(vb+fr,fq*16));
      f32x4 dl=mf(At,Bt,z4);
      int s0=16*i+fq*4;
      uint2 wd; wd.x=packbf(dl[0],dl[1]); wd.y=packbf(dl[2],dl[3]);
      *(uint2*)(sm+aDT(vb+fr,s0*2))=wd;
      uint2 ww; ww.x=packbf(dl[0]*WV[s0],dl[1]*WV[s0+1]); ww.y=packbf(dl[2]*WV[s0+2],dl[3]*WV[s0+3]);
      *(uint2*)(sm+aWMT(vb+fr,s0*2))=ww;
    }
  }
  __syncthreads();   // E
  {
    u16* aout = aqmg + (size_t)b*4096;   // swizzled [64][64] for k_state LDS path
#pragma unroll
    for(int ts=0;ts<4;++ts){
      f32x4 acc=z4;
#pragma unroll
      for(int jp=0;jp<2;++jp){
        bf16x8 A=*(const bf16x8*)(sm+aAQ(16*wave+fr,jp*64+fq*16));
        bf16x8 B=*(const bf16x8*)(sm+aDT(16*ts+fr,jp*64+fq*16));
        acc=mf(A,B,acc);
      }
#pragma unroll
      for(int p=0;p<4;++p){
        int t=16*wave+fq*4+p, s=16*ts+fr;
        aout[(t*128 + ((s*2)^((t&7)<<4)))>>1]=f2bf(acc[p]);
      }
    }
    u16* kout = kwmg + (size_t)b*8192;   // swizzled [128][64]
#pragma unroll
    for(int j=0;j<2;++j){
      int dt=wave+4*j;
#pragma unroll
      for(int st=0;st<4;++st){
        f32x4 acc=z4;
#pragma unroll
        for(int jp=0;jp<2;++jp){
          bf16x8 A=*(const bf16x8*)(sm+aKT(16*dt+fr,jp*64+fq*16));
          bf16x8 B=*(const bf16x8*)(sm+aWMT(16*st+fr,jp*64+fq*16));
          acc=mf(A,B,acc);
        }
#pragma unroll
        for(int p=0;p<4;++p){
          int d=16*dt+fq*4+p, s=16*st+fr;
          kout[(d*128 + ((s*2)^((d&7)<<4)))>>1]=f2bf(acc[p]);
        }
      }
    }
  }
}

// ================ P2: sequential state pass — stage at chunk top, raw mid barrier ================
// stage(c+1) writes buffer b^1 whose readers all completed before the end-of-(c-1)
// full __syncthreads. Mid barrier only needs R0T visibility: lgkmcnt(0)+s_barrier
// (staging stays in flight across both phases). End barrier = __syncthreads (full drain).
#define P2_K(b)   ((b)*16384)
#define P2_Q(b)   (32768 + (b)*16384)
#define P2_W(b)   (65536 + (b)*16384)
#define P2_M(b)   (98304 + (b)*8192)
#define P2_TAB(b) (114688 + (b)*1024)
#define P2_ST(b)  (116736 + (b)*4096)
#define P2_R0T    124928
#define P2_SIZE   126976

#define bKx(b,r,cb)  (P2_K(b) + (r)*256 + SW7(r,cb))
#define bQx(b,r,cb)  (P2_Q(b) + (r)*256 + SW7(r,cb))
#define bWx(b,d,cb)  (P2_W(b) + (d)*128 + SW7(d,cb))
#define bMx(b,t,cb)  (P2_M(b) + (t)*128 + SW7(t,cb))
#define bSTx(b,v,cb) (P2_ST(b) + (v)*256 + SW7(v,cb))
#define bRx(v,cb)    (P2_R0T + (v)*128 + SW7(v,cb))

__global__ __launch_bounds__(256) void k_state(const u16* __restrict__ qn, const u16* __restrict__ kn,
    const u16* __restrict__ vv, const u16* __restrict__ aqmg, const u16* __restrict__ kwmg,
    const float* __restrict__ tabg, u16* __restrict__ ob){
  extern __shared__ char sm[];
  const int tid=threadIdx.x, lane=tid&63, wave=tid>>6;
  const int fr=lane&15, fq=lane>>4;
  const int h=blockIdx.x&31, vs=(blockIdx.x>>5)*16, kh=h>>1;
  const f32x4 z4={0.f,0.f,0.f,0.f};
  for(int off=116736+tid*16; off<124928; off+=4096) *(uint4*)(sm+off)=make_uint4(0,0,0,0);

  auto stage=[&](int c,int b){
    int srow=wave*4+(lane>>4);
    int pb2=(lane&15)*16;
#pragma unroll
    for(int r=0;r<4;++r){
      int row=r*16+srow;
      int gcb=pb2^((row&7)<<4);
      gld16((const char*)kn + ((size_t)((c<<6)+row)*KEY_DIM + kh*DKn)*2 + gcb, sm + P2_K(b)+r*4096+wave*1024);
      gld16((const char*)qn + ((size_t)((c<<6)+row)*KEY_DIM + kh*DKn)*2 + gcb, sm + P2_Q(b)+r*4096+wave*1024);
    }
    const char* wsrc=(const char*)kwmg + (size_t)(h*64+c)*16384;
#pragma unroll
    for(int r=0;r<4;++r)
      gld16(wsrc + r*4096 + wave*1024 + lane*16, sm + P2_W(b)+r*4096+wave*1024);
    const char* msrc=(const char*)aqmg + (size_t)(h*64+c)*8192;
#pragma unroll
    for(int r=0;r<2;++r)
      gld16(msrc + r*4096 + wave*1024 + lane*16, sm + P2_M(b)+r*4096+wave*1024);
    if(wave==0)
      gld16((const char*)tabg + (size_t)(h*64+c)*768 + lane*16, sm + P2_TAB(b));
  };
  u16 vl[4];
  auto loadV=[&](int c){
#pragma unroll
    for(int p=0;p<4;++p)
      vl[p]=vv[(size_t)((c<<6)+16*wave+fq*4+p)*VAL_DIM + h*DVn + vs + fr];
  };

  f32x4 S0=z4, S1=z4;
  stage(0,0); loadV(0);
  __syncthreads();

  for(int c=0;c<64;++c){
    int b=c&1;
    const float* TBf=(const float*)(sm+P2_TAB(b));
    if(c<63) stage(c+1,b^1);                 // staging spans both phases
    f32x4 ks=z4;
#pragma unroll
    for(int kk=0;kk<4;++kk)
      ks=mf(*(const bf16x8*)(sm+bKx(b,16*wave+fr,kk*64+fq*16)),
            *(const bf16x8*)(sm+bSTx(b,fr,kk*64+fq*16)), ks);
    float r0v[4];
#pragma unroll
    for(int p=0;p<4;++p){
      int t=16*wave+fq*4+p;
      r0v[p]=TBf[64+t]*(bf2f(vl[p]) - TBf[t]*ks[p]);
    }
    uint2 rw; rw.x=packbf(r0v[0],r0v[1]); rw.y=packbf(r0v[2],r0v[3]);
    *(uint2*)(sm+bRx(fr,32*wave+8*fq))=rw;
    asm volatile("s_waitcnt lgkmcnt(0)":::"memory");
    __builtin_amdgcn_s_barrier();            // mid: R0T visible; staging in flight
    f32x4 qs=z4;
#pragma unroll
    for(int kk=0;kk<4;++kk)
      qs=mf(*(const bf16x8*)(sm+bQx(b,16*wave+fr,kk*64+fq*16)),
            *(const bf16x8*)(sm+bSTx(b,fr,kk*64+fq*16)), qs);
#pragma unroll
    for(int p=0;p<4;++p) qs[p]*=TBf[16*wave+fq*4+p];
#pragma unroll
    for(int jp=0;jp<2;++jp)
      qs=mf(*(const bf16x8*)(sm+bMx(b,16*wave+fr,jp*64+fq*16)),
            *(const bf16x8*)(sm+bRx(fr,jp*64+fq*16)), qs);
#pragma unroll
    for(int p=0;p<4;++p)
      ob[(size_t)((c<<6)+16*wave+fq*4+p)*VAL_DIM + h*DVn + vs + fr]=f2bf(qs[p]);
    if(c<63) loadV(c+1);
    float gl=TBf[128];
    S0[0]*=gl;S0[1]*=gl;S0[2]*=gl;S0[3]*=gl;
    S1[0]*=gl;S1[1]*=gl;S1[2]*=gl;S1[3]*=gl;
#pragma unroll
    for(int jp=0;jp<2;++jp){
      bf16x8 Br=*(const bf16x8*)(sm+bRx(fr,jp*64+fq*16));
      S0=mf(*(const bf16x8*)(sm+bWx(b,16*wave+fr,jp*64+fq*16)), Br, S0);
      S1=mf(*(const bf16x8*)(sm+bWx(b,16*(wave+4)+fr,jp*64+fq*16)), Br, S1);
    }
    uint2 s0w; s0w.x=packbf(S0[0],S0[1]); s0w.y=packbf(S0[2],S0[3]);
    *(uint2*)(sm+bSTx(b^1,fr,32*wave+8*fq))=s0w;
    uint2 s1w; s1w.x=packbf(S1[0],S1[1]); s1w.y=packbf(S1[2],S1[3]);
    *(uint2*)(sm+bSTx(b^1,fr,32*(wave+4)+8*fq))=s1w;
    __syncthreads();                         // end: full drain (staged b^1 + ST ready)
  }
}

// ---------------- gated RMSNorm * silu(z) -> bf16 (bf16 input) ----------------
__global__ __launch_bounds__(256) void k_gnorm(const u16* __restrict__ ob, const u16* __restrict__ zq,
    const float* __restrict__ nw, u16* __restrict__ og){
  int t = blockIdx.x;
  int base = threadIdx.x*16;
  const u16* src = ob + (size_t)t*VAL_DIM + base;
  uint4 a0 = *(const uint4*)src;
  uint4 a1 = *(const uint4*)(src+8);
  u32 xr[8] = {a0.x,a0.y,a0.z,a0.w,a1.x,a1.y,a1.z,a1.w};
  float x[16];
#pragma unroll
  for (int p=0;p<8;++p){ x[2*p]=bf2f(xr[p]&0xffffu); x[2*p+1]=bf2f(xr[p]>>16); }
  float ss=0.f;
#pragma unroll
  for (int i=0;i<16;++i) ss += x[i]*x[i];
  ss += __shfl_xor(ss,1); ss += __shfl_xor(ss,2); ss += __shfl_xor(ss,4);
  float rs = 1.f/sqrtf(ss*(1.f/128.f) + 1e-6f);
  const u16* zp = zq + (size_t)t*VAL_DIM + base;
  uint4 z0 = *(const uint4*)zp;
  uint4 z1 = *(const uint4*)(zp+8);
  u32 zr[8] = {z0.x,z0.y,z0.z,z0.w,z1.x,z1.y,z1.z,z1.w};
  u32 outw[8];
#pragma unroll
  for (int p=0;p<8;++p){
    float za = bf2f(zr[p]&0xffffu), zb = bf2f(zr[p]>>16);
    float sa = za/(1.f+__expf(-za)), sb = zb/(1.f+__expf(-zb));
    int i0 = p*2, i1 = p*2+1;
    float oa = x[i0]*rs*nw[(base+i0)&127]*sa;
    float obv = x[i1]*rs*nw[(base+i1)&127]*sb;
    outw[p] = packbf(oa, obv);
  }
  uint4* dst = (uint4*)(og + (size_t)t*VAL_DIM + base);
  dst[0] = make_uint4(outw[0],outw[1],outw[2],outw[3]);
  dst[1] = make_uint4(outw[4],outw[5],outw[6],outw[7]);
}

extern "C" void kernel_launch(void* const* d_in, const int* in_sizes, int n_in,
                              void* d_out, int out_size, void* d_ws, size_t ws_size,
                              hipStream_t stream) {
  const float* hidden  = (const float*)d_in[0];
  const float* W_qkvz  = (const float*)d_in[1];
  const float* W_ba    = (const float*)d_in[2];
  const float* conv_w  = (const float*)d_in[3];
  const float* A_log   = (const float*)d_in[4];
  const float* dt_bias = (const float*)d_in[5];
  const float* norm_w  = (const float*)d_in[6];
  const float* W_out   = (const float*)d_in[7];

  char* w = (char*)d_ws;
  size_t need = 252706816;
  if (ws_size < need) return;

  u16*   Xb   = (u16*)(w + 0);
  u16*   W1T  = (u16*)(w + 16777216);
  u16*   QKV  = (u16*)(w + 67108864);
  u16*   Z    = (u16*)(w + 134217728);
  u16*   QN   = (u16*)(w + 167772160);
  u16*   KN   = (u16*)(w + 184549376);
  u16*   V    = (u16*)(w + 201326592);
  u16*   WoT  = (u16*)(w + 234881024);
  float* GTb  = (float*)(w + 251658240);
  float* BTb  = (float*)(w + 252182528);
  u16*   OB   = (u16*)(w + 0);
  u16*   AQMg = (u16*)(w + 67108864);
  u16*   KWMg = (u16*)(w + 83886080);
  float* TABg = (float*)(w + 117440512);
  u16*   OG   = (u16*)(w + 167772160);

  static int smem_set = 0;
  if (!smem_set){
    hipFuncSetAttribute((const void*)k_prep,  hipFuncAttributeMaxDynamicSharedMemorySize, P1_SIZE);
    hipFuncSetAttribute((const void*)k_state, hipFuncAttributeMaxDynamicSharedMemorySize, P2_SIZE);
    hipFuncSetAttribute((const void*)k_g256<1>, hipFuncAttributeMaxDynamicSharedMemorySize, G2_LDS);
    hipFuncSetAttribute((const void*)k_gw, hipFuncAttributeMaxDynamicSharedMemorySize, GW_LDS);
    smem_set = 1;
  }

  k_cvt<<<4096,256,0,stream>>>(hidden, Xb, T_LEN*H_DIM);
  k_tcvt<<<dim3(12288/32, H_DIM/32),256,0,stream>>>(W_qkvz, W1T, H_DIM, 12288);
  k_tcvt<<<dim3(H_DIM/32, VAL_DIM/32),256,0,stream>>>(W_out, WoT, VAL_DIM, H_DIM);
  k_ba<<<T_LEN/4,256,0,stream>>>(hidden, W_ba, A_log, dt_bias, GTb, BTb);
  k_g256<1><<<768,512,G2_LDS,stream>>>(Xb, W1T, QKV, Z, 8192, T_LEN, 12288, H_DIM);
  k_conv<<<dim3(128,4),256,0,stream>>>(QKV, conv_w, QN, KN, V);
  k_prep<<<2048,256,P1_SIZE,stream>>>(QN, KN, GTb, BTb, AQMg, KWMg, TABg);
  k_state<<<256,256,P2_SIZE,stream>>>(QN, KN, V, AQMg, KWMg, TABg, OB);
  k_gnorm<<<T_LEN,256,0,stream>>>(OB, Z, norm_w, OG);
  k_gw<<<256,512,GW_LDS,stream>>>(OG, WoT, (float*)d_out, T_LEN, H_DIM, VAL_DIM);
}

// Round 21
// 662.573 us; speedup vs baseline: 1.0172x; 1.0172x over previous
//
#include <hip/hip_runtime.h>
#include <hip/hip_bf16.h>

#define T_LEN 4096
#define H_DIM 2048
#define HKn 16
#define HVn 32
#define DKn 128
#define DVn 128
#define KEY_DIM 2048
#define VAL_DIM 4096

typedef unsigned int u32;
typedef unsigned short u16;
typedef __attribute__((ext_vector_type(8))) short bf16x8;
typedef __attribute__((ext_vector_type(4))) float f32x4;

__device__ __forceinline__ u16 f2bf(float x){
  u32 u = __float_as_uint(x);
  u32 r = (u + 0x7fffu + ((u>>16)&1u)) >> 16;
  return (u16)r;
}
__device__ __forceinline__ float bf2f(u32 b){ return __uint_as_float(b<<16); }
__device__ __forceinline__ u32 packbf(float a, float b){ return (u32)f2bf(a) | ((u32)f2bf(b)<<16); }

// ---------------- fp32 -> bf16 elementwise ----------------
__global__ __launch_bounds__(256) void k_cvt(const float* __restrict__ in, u16* __restrict__ out, int n){
  int i = (blockIdx.x*256 + threadIdx.x)*8;
  if (i >= n) return;
  float4 a = *(const float4*)(in+i);
  float4 b = *(const float4*)(in+i+4);
  uint4 o;
  o.x = packbf(a.x,a.y); o.y = packbf(a.z,a.w);
  o.z = packbf(b.x,b.y); o.w = packbf(b.z,b.w);
  *(uint4*)(out+i) = o;
}

// ---------------- fp32 [R][C] -> bf16 transposed [C][R] ----------------
__global__ __launch_bounds__(256) void k_tcvt(const float* __restrict__ in, u16* __restrict__ out, int R, int C){
  __shared__ float tile[32][33];
  int c0 = blockIdx.x*32, r0 = blockIdx.y*32;
  int tx = threadIdx.x & 31, ty = threadIdx.x >> 5;
#pragma unroll
  for (int i=0;i<4;++i) tile[ty+8*i][tx] = in[(size_t)(r0+ty+8*i)*C + c0+tx];
  __syncthreads();
#pragma unroll
  for (int i=0;i<4;++i) out[(size_t)(c0+ty+8*i)*R + r0+tx] = f2bf(tile[tx][ty+8*i]);
}

// ---------------- ba = X @ W_ba  ->  gT [HVn][T], bT [HVn][T] ----------------
__global__ __launch_bounds__(256) void k_ba(const float* __restrict__ X, const float* __restrict__ W,
    const float* __restrict__ A_log, const float* __restrict__ dt_bias,
    float* __restrict__ gT, float* __restrict__ bT){
  int tid = threadIdx.x;
  int t = blockIdx.x*4 + (tid>>6);
  int j = tid & 63;
  const float* xr = X + (size_t)t*H_DIM;
  float acc = 0.f;
  for (int k=0;k<H_DIM;k+=4){
    float4 xv = *(const float4*)(xr+k);
    acc += xv.x*W[(size_t)(k+0)*64 + j];
    acc += xv.y*W[(size_t)(k+1)*64 + j];
    acc += xv.z*W[(size_t)(k+2)*64 + j];
    acc += xv.w*W[(size_t)(k+3)*64 + j];
  }
  if (j < HVn) {
    bT[(size_t)j*T_LEN + t] = 1.f/(1.f+__expf(-acc));
  } else {
    int h = j - HVn;
    float x = acc + dt_bias[h];
    float sp = (x > 20.f) ? x : log1pf(__expf(x));
    gT[(size_t)h*T_LEN + t] = -__expf(A_log[h]) * sp;
  }
}

typedef const __attribute__((address_space(1))) u32* gas_t;
typedef __attribute__((address_space(3))) u32* las_t;
__device__ __forceinline__ void gld16(const void* g, void* l){
  __builtin_amdgcn_global_load_lds((gas_t)g, (las_t)l, 16, 0, 0);
}
__device__ __forceinline__ f32x4 mf(bf16x8 a, bf16x8 b, f32x4 c){
  return __builtin_amdgcn_mfma_f32_16x16x32_bf16(a,b,c,0,0,0);
}

// ================ 256^2-tile GEMM (GEMM1), tail-fixed (R18) ================
#define G2_LDS 131072
#define SWX(a) ((a) ^ ((((a)>>9)&1)<<5))

template<int WRITE_BF16>
__global__ __launch_bounds__(512) void k_g256(const u16* __restrict__ A, const u16* __restrict__ BT,
    void* __restrict__ C1, void* __restrict__ C2, int NS, int M, int N, int K){
  extern __shared__ char sm[];
  const int tid=threadIdx.x, lane=tid&63, wave=tid>>6;
  const int fr=lane&15, fq=lane>>4;
  const int wm=wave>>2, wn=wave&3;
  const int nbm = M>>8, nwg = nbm*(N>>8);
  const int cpx = nwg>>3;
  const int swz = ((int)blockIdx.x & 7)*cpx + ((int)blockIdx.x >> 3);  // nwg%8==0
  const int m0 = (swz % nbm) << 8, n0 = (swz / nbm) << 8;
  const int NK = K >> 5;

  f32x4 acc[8][4];
#pragma unroll
  for (int i=0;i<8;++i)
#pragma unroll
    for (int j=0;j<4;++j) acc[i][j] = (f32x4){0.f,0.f,0.f,0.f};

  auto stageA=[&](int kt){
    char* base = sm + (size_t)(kt&3)*32768;
#pragma unroll
    for (int ld=0; ld<2; ++ld){
      int p = ld*8192 + wave*1024 + lane*16;
      int a = SWX(p);
      gld16((const char*)A + ((size_t)(m0 + (a>>6))*K + kt*32)*2 + (a&63), base + p);
    }
  };
  auto stageB=[&](int kt){
    char* base = sm + (size_t)(kt&3)*32768 + 16384;
#pragma unroll
    for (int ld=0; ld<2; ++ld){
      int p = ld*8192 + wave*1024 + lane*16;
      int a = SWX(p);
      gld16((const char*)BT + ((size_t)(n0 + (a>>6))*K + kt*32)*2 + (a&63), base + p);
    }
  };

  stageA(0); stageB(0); stageA(1); stageB(1); stageA(2); stageB(2);
  __syncthreads();

  for (int kt=0; kt<NK; ++kt){
    const char* bufA = sm + (size_t)(kt&3)*32768;
    const char* bufB = bufA + 16384;
    const int ksn = (kt+3 < NK) ? kt+3 : kt+3-NK;
    bf16x8 bfr[4], afr[4];
#pragma unroll
    for (int j=0;j<4;++j){
      int a = (wn*64 + j*16 + fr)*64 + fq*16;
      bfr[j] = *(const bf16x8*)(bufB + SWX(a));
    }
#pragma unroll
    for (int i=0;i<4;++i){
      int a = (wm*128 + i*16 + fr)*64 + fq*16;
      afr[i] = *(const bf16x8*)(bufA + SWX(a));
    }
    {  // stageA into buffer (kt+3)&3 from source tile ksn
      char* base = sm + (size_t)((kt+3)&3)*32768;
#pragma unroll
      for (int ld=0; ld<2; ++ld){
        int p = ld*8192 + wave*1024 + lane*16;
        int a = SWX(p);
        gld16((const char*)A + ((size_t)(m0 + (a>>6))*K + ksn*32)*2 + (a&63), base + p);
      }
    }
    asm volatile("s_barrier" ::: "memory");
    __builtin_amdgcn_s_setprio(1);
#pragma unroll
    for (int i=0;i<4;++i)
#pragma unroll
      for (int j=0;j<4;++j) acc[i][j] = mf(afr[i], bfr[j], acc[i][j]);
    __builtin_amdgcn_s_setprio(0);
    asm volatile("s_barrier" ::: "memory");
#pragma unroll
    for (int i=0;i<4;++i){
      int a = (wm*128 + 64 + i*16 + fr)*64 + fq*16;
      afr[i] = *(const bf16x8*)(bufA + SWX(a));
    }
    {  // stageB into buffer (kt+3)&3 from source tile ksn
      char* base = sm + (size_t)((kt+3)&3)*32768 + 16384;
#pragma unroll
      for (int ld=0; ld<2; ++ld){
        int p = ld*8192 + wave*1024 + lane*16;
        int a = SWX(p);
        gld16((const char*)BT + ((size_t)(n0 + (a>>6))*K + ksn*32)*2 + (a&63), base + p);
      }
    }
    asm volatile("s_barrier" ::: "memory");
    __builtin_amdgcn_s_setprio(1);
#pragma unroll
    for (int i=0;i<4;++i)
#pragma unroll
      for (int j=0;j<4;++j) acc[4+i][j] = mf(afr[i], bfr[j], acc[4+i][j]);
    __builtin_amdgcn_s_setprio(0);
    asm volatile("s_waitcnt vmcnt(8)" ::: "memory");
    asm volatile("s_barrier" ::: "memory");
  }

  const int inc1 = (n0 < NS);
  const int ldc = inc1 ? NS : (N - NS);
  const int nb  = inc1 ? n0 : (n0 - NS);
  u16*   Cb16 = (u16*)(inc1 ? C1 : C2);
  float* Cbf  = (float*)(inc1 ? C1 : C2);
#pragma unroll
  for (int mt=0; mt<8; ++mt)
#pragma unroll
    for (int nt=0; nt<4; ++nt){
      int row = m0 + wm*128 + mt*16 + fq*4;
      int col = nb + wn*64 + nt*16 + fr;
#pragma unroll
      for (int r=0;r<4;++r){
        float v = acc[mt][nt][r];
        if (WRITE_BF16) Cb16[(size_t)(row+r)*ldc + col] = f2bf(v);
        else            Cbf [(size_t)(row+r)*ldc + col] = v;
      }
    }
}

// ================ 128x256-tile GEMM (GEMM2), tail-fixed (R18) ================
#define GW_LDS 98304
__global__ __launch_bounds__(512) void k_gw(const u16* __restrict__ A, const u16* __restrict__ BT,
    float* __restrict__ C, int M, int N, int K){
  extern __shared__ char sm[];
  const int tid=threadIdx.x, lane=tid&63, wave=tid>>6;
  const int fr=lane&15, fq=lane>>4;
  const int wm=wave>>2, wn=wave&3;
  const int nbm=M>>7, nwg=nbm*(N>>8);
  const int cpx=nwg>>3;
  const int swz=((int)blockIdx.x&7)*cpx + ((int)blockIdx.x>>3);   // nwg%8==0
  const int m0=(swz%nbm)<<7, n0=(swz/nbm)<<8;
  const int NK=K>>5;

  f32x4 acc[4][4];
#pragma unroll
  for(int i=0;i<4;++i)
#pragma unroll
    for(int j=0;j<4;++j) acc[i][j]=(f32x4){0.f,0.f,0.f,0.f};

  auto stage=[&](int kt, int buf){
    char* base = sm + (size_t)buf*24576;
    { int p=tid*16; int a=SWX(p);
      gld16((const char*)A + ((size_t)(m0+(a>>6))*K + kt*32)*2 + (a&63), base+p); }
    char* bb = base + 8192;
#pragma unroll
    for(int ld=0;ld<2;++ld){ int p=ld*8192+tid*16; int a=SWX(p);
      gld16((const char*)BT + ((size_t)(n0+(a>>6))*K + kt*32)*2 + (a&63), bb+p); }
  };
  stage(0,0); stage(1,1); stage(2,2);
  __syncthreads();

  for(int kt=0;kt<NK;++kt){
    const char* bufA = sm + (size_t)(kt&3)*24576;
    const char* bufB = bufA + 8192;
    bf16x8 afr[4], bfr[4];
#pragma unroll
    for(int i=0;i<4;++i){ int a=(wm*64+i*16+fr)*64+fq*16; afr[i]=*(const bf16x8*)(bufA+SWX(a)); }
#pragma unroll
    for(int j=0;j<4;++j){ int a=(wn*64+j*16+fr)*64+fq*16; bfr[j]=*(const bf16x8*)(bufB+SWX(a)); }
    { int ksn=(kt+3<NK)?kt+3:kt+3-NK; stage(ksn,(kt+3)&3); }
    asm volatile("s_barrier":::"memory");
    __builtin_amdgcn_s_setprio(1);
#pragma unroll
    for(int i=0;i<4;++i)
#pragma unroll
      for(int j=0;j<4;++j) acc[i][j]=mf(afr[i],bfr[j],acc[i][j]);
    __builtin_amdgcn_s_setprio(0);
    asm volatile("s_waitcnt vmcnt(6)":::"memory");
    asm volatile("s_barrier":::"memory");
  }

#pragma unroll
  for(int mt=0;mt<4;++mt)
#pragma unroll
    for(int nt=0;nt<4;++nt){
      int row=m0+wm*64+mt*16+fq*4;
      int col=n0+wn*64+nt*16+fr;
#pragma unroll
      for(int r=0;r<4;++r)
        C[(size_t)(row+r)*N + col] = acc[mt][nt][r];
    }
}

// ------- causal conv(KW=4)+SiLU+l2norm, one-pass rolling registers -------
__global__ __launch_bounds__(256) void k_conv(const u16* __restrict__ qkv, const float* __restrict__ cw,
    u16* __restrict__ qn, u16* __restrict__ kn, u16* __restrict__ vv){
  const int r = blockIdx.y;
  const int t0 = blockIdx.x*32;
  const int c = r*2048 + threadIdx.x*8;
  float wgt[8][4];
#pragma unroll
  for(int i=0;i<8;++i){
    float4 wv=*(const float4*)(cw+(size_t)(c+i)*4);
    wgt[i][0]=wv.x;wgt[i][1]=wv.y;wgt[i][2]=wv.z;wgt[i][3]=wv.w;
  }
  float h0[8],h1[8],h2[8];
  if(t0>=3){
    uint4 a=*(const uint4*)(qkv+(size_t)(t0-3)*8192+c);
    uint4 b=*(const uint4*)(qkv+(size_t)(t0-2)*8192+c);
    uint4 d=*(const uint4*)(qkv+(size_t)(t0-1)*8192+c);
    h0[0]=bf2f(a.x&0xffffu);h0[1]=bf2f(a.x>>16);h0[2]=bf2f(a.y&0xffffu);h0[3]=bf2f(a.y>>16);
    h0[4]=bf2f(a.z&0xffffu);h0[5]=bf2f(a.z>>16);h0[6]=bf2f(a.w&0xffffu);h0[7]=bf2f(a.w>>16);
    h1[0]=bf2f(b.x&0xffffu);h1[1]=bf2f(b.x>>16);h1[2]=bf2f(b.y&0xffffu);h1[3]=bf2f(b.y>>16);
    h1[4]=bf2f(b.z&0xffffu);h1[5]=bf2f(b.z>>16);h1[6]=bf2f(b.w&0xffffu);h1[7]=bf2f(b.w>>16);
    h2[0]=bf2f(d.x&0xffffu);h2[1]=bf2f(d.x>>16);h2[2]=bf2f(d.y&0xffffu);h2[3]=bf2f(d.y>>16);
    h2[4]=bf2f(d.z&0xffffu);h2[5]=bf2f(d.z>>16);h2[6]=bf2f(d.w&0xffffu);h2[7]=bf2f(d.w>>16);
  } else {
#pragma unroll
    for(int i=0;i<8;++i){h0[i]=0.f;h1[i]=0.f;h2[i]=0.f;}
  }
  uint4 c0=*(const uint4*)(qkv+(size_t)t0*8192+c);
  uint4 c1=*(const uint4*)(qkv+(size_t)(t0+1)*8192+c);
  uint4 c2=*(const uint4*)(qkv+(size_t)(t0+2)*8192+c);
  for(int it=0; it<32; ++it){
    int t=t0+it;
    uint4 cn = (t+3<T_LEN)? *(const uint4*)(qkv+(size_t)(t+3)*8192+c) : c0;
    float cur[8];
    cur[0]=bf2f(c0.x&0xffffu);cur[1]=bf2f(c0.x>>16);cur[2]=bf2f(c0.y&0xffffu);cur[3]=bf2f(c0.y>>16);
    cur[4]=bf2f(c0.z&0xffffu);cur[5]=bf2f(c0.z>>16);cur[6]=bf2f(c0.w&0xffffu);cur[7]=bf2f(c0.w>>16);
    float y[8];
#pragma unroll
    for(int i=0;i<8;++i)
      y[i]=fmaf(h0[i],wgt[i][0],fmaf(h1[i],wgt[i][1],fmaf(h2[i],wgt[i][2],cur[i]*wgt[i][3])));
#pragma unroll
    for(int i=0;i<8;++i) y[i]=y[i]/(1.f+__expf(-y[i]));
    if(r<=1){
      float ss=0.f;
#pragma unroll
      for(int i=0;i<8;++i) ss+=y[i]*y[i];
      ss+=__shfl_xor(ss,1);ss+=__shfl_xor(ss,2);ss+=__shfl_xor(ss,4);ss+=__shfl_xor(ss,8);
      float sc=1.f/sqrtf(ss+1e-6f);
      if(r==0) sc*=0.08838834764831845f;
#pragma unroll
      for(int i=0;i<8;++i) y[i]*=sc;
      u16* dst=(r==0?qn:kn)+(size_t)t*KEY_DIM+(c-r*2048);
      *(uint4*)dst=make_uint4(packbf(y[0],y[1]),packbf(y[2],y[3]),packbf(y[4],y[5]),packbf(y[6],y[7]));
    } else {
      u16* dst=vv+(size_t)t*VAL_DIM+(c-4096);
      *(uint4*)dst=make_uint4(packbf(y[0],y[1]),packbf(y[2],y[3]),packbf(y[4],y[5]),packbf(y[6],y[7]));
    }
#pragma unroll
    for(int i=0;i<8;++i){h0[i]=h1[i];h1[i]=h2[i];h2[i]=cur[i];}
    c0=c1;c1=c2;c2=cn;
  }
}

// ================ P1: per-chunk operator precompute (2 blocks/CU, swizzled outputs) ================
#define P1_K    0
#define P1_Q    16384
#define P1_DT   16384
#define P1_WMT  24576
#define P1_KT   32768
#define P1_NBP  49152
#define P1_AQ   57344
#define P1_NBD  65536
#define P1_TII  69632
#define P1_R1T  73728
#define P1_TAB  77824
#define P1_SIZE 78912

#define SW7(r,cb) ((cb) ^ (((r)&7)<<4))
#define SW3(r,cb) ((cb) ^ (((r)&3)<<4))
#define aK(r,cb)   (P1_K   + (r)*256 + SW7(r,cb))
#define aQ2(r,cb)  (P1_Q   + (r)*256 + SW7(r,cb))
#define aKT(d,cb)  (P1_KT  + (d)*128 + SW7(d,cb))
#define aNBP(t,cb) (P1_NBP + (t)*128 + SW7(t,cb))
#define aAQ(t,cb)  (P1_AQ  + (t)*128 + SW7(t,cb))
#define aDT(s,cb)  (P1_DT  + (s)*128 + SW7(s,cb))
#define aWMT(s,cb) (P1_WMT + (s)*128 + SW7(s,cb))
#define aTII(b,r,cb) (P1_TII + (b)*1024 + (r)*64 + SW3(r,cb))
#define aR1T(v,cb)   (P1_R1T + (v)*64 + SW3(v,cb))

__global__ __launch_bounds__(256) void k_prep(const u16* __restrict__ qn, const u16* __restrict__ kn,
    const float* __restrict__ gT, const float* __restrict__ bT,
    u16* __restrict__ aqmg, u16* __restrict__ kwmg, float* __restrict__ tabg){
  extern __shared__ char sm[];
  const int tid=threadIdx.x, lane=tid&63, wave=tid>>6;
  const int fr=lane&15, fq=lane>>4;
  const int b=blockIdx.x, h=b>>6, c=b&63, kh=h>>1;
  const f32x4 z4={0.f,0.f,0.f,0.f};
  for (int off=P1_NBD+tid*16; off<P1_TAB; off+=4096) *(uint4*)(sm+off)=make_uint4(0,0,0,0);
  {
    int srow = wave*4 + (lane>>4);
    int pb = (lane&15)*16;
#pragma unroll
    for (int r=0;r<4;++r){
      int row=r*16+srow;
      int gcb = pb ^ ((row&7)<<4);
      gld16((const char*)kn + ((size_t)((c<<6)+row)*KEY_DIM + kh*DKn)*2 + gcb, sm + P1_K + r*4096 + wave*1024);
      gld16((const char*)qn + ((size_t)((c<<6)+row)*KEY_DIM + kh*DKn)*2 + gcb, sm + P1_Q + r*4096 + wave*1024);
    }
  }
  float* TB=(float*)(sm+P1_TAB);
  if (wave==0){
    int t=lane;
    float gv=gT[(size_t)h*T_LEN+(c<<6)+t];
    float bv=bT[(size_t)h*T_LEN+(c<<6)+t];
    float s=gv;
    for(int o2=1;o2<64;o2<<=1){ float u=__shfl_up(s,o2,64); if(lane>=o2) s+=u; }
    float cgL=__shfl(s,63,64);
    float gam=__expf(s);
    TB[t]=s; TB[64+t]=gam; TB[128+t]=__expf(cgL-s); TB[192+t]=bv;
    float* tg=tabg+(size_t)b*192;
    tg[t]=gam; tg[64+t]=bv;
    if(t==0) tg[128]=__expf(cgL);
  }
  __syncthreads();
#pragma unroll
  for (int dd=0;dd<2;++dd){
    int tp=tid&31, d0=((tid>>5)+dd*8)*8;
    bf16x8 r0=*(const bf16x8*)(sm+aK(2*tp,d0*2));
    bf16x8 r1=*(const bf16x8*)(sm+aK(2*tp+1,d0*2));
#pragma unroll
    for(int j=0;j<8;++j){
      u32 pk=((u32)(u16)r0[j])|((u32)(u16)r1[j]<<16);
      *(u32*)(sm+aKT(d0+j,tp*4))=pk;
    }
  }
  const int ra=(wave>>1)*32, rb=(wave&1)*32;
  f32x4 kq[2][2], qk[2][2];
#pragma unroll
  for(int ta=0;ta<2;++ta)
#pragma unroll
  for(int tb=0;tb<2;++tb){ kq[ta][tb]=z4; qk[ta][tb]=z4; }
#pragma unroll
  for(int kk=0;kk<4;++kk){
    int cb=kk*64+fq*16;
    bf16x8 Ak0=*(const bf16x8*)(sm+aK(ra+fr,cb));
    bf16x8 Ak1=*(const bf16x8*)(sm+aK(ra+16+fr,cb));
    bf16x8 Aq0=*(const bf16x8*)(sm+aQ2(ra+fr,cb));
    bf16x8 Aq1=*(const bf16x8*)(sm+aQ2(ra+16+fr,cb));
    bf16x8 Bk0=*(const bf16x8*)(sm+aK(rb+fr,cb));
    bf16x8 Bk1=*(const bf16x8*)(sm+aK(rb+16+fr,cb));
    if(ra>=rb)      { kq[0][0]=mf(Ak0,Bk0,kq[0][0]); qk[0][0]=mf(Aq0,Bk0,qk[0][0]); }
    if(ra>=rb+16)   { kq[0][1]=mf(Ak0,Bk1,kq[0][1]); qk[0][1]=mf(Aq0,Bk1,qk[0][1]); }
    if(ra+16>=rb)   { kq[1][0]=mf(Ak1,Bk0,kq[1][0]); qk[1][0]=mf(Aq1,Bk0,qk[1][0]); }
    if(ra+16>=rb+16){ kq[1][1]=mf(Ak1,Bk1,kq[1][1]); qk[1][1]=mf(Aq1,Bk1,qk[1][1]); }
  }
  {
    const float* cg=TB; const float* Be=TB+192;
#pragma unroll
    for(int ta=0;ta<2;++ta)
#pragma unroll
    for(int tb=0;tb<2;++tb){
      int tab=ra+16*ta, tbb=rb+16*tb;
#pragma unroll
      for(int p=0;p<4;++p){
        int t=tab+fq*4+p, s2=tbb+fr;
        float e=__expf(cg[t]-cg[s2]);
        float nv=(s2<t)? -Be[t]*kq[ta][tb][p]*e : 0.f;
        *(u16*)(sm+aNBP(t,s2*2)) = (tbb<tab)? f2bf(nv):(u16)0;
        if(tbb==tab) ((float*)(sm+P1_NBD))[(tab>>4)*256+(fq*4+p)*16+fr]=nv;
        float av=(s2<=t)? qk[ta][tb][p]*e : 0.f;
        *(u16*)(sm+aAQ(t,s2*2)) = f2bf(av);
      }
    }
  }
  __syncthreads();   // C2: Q dead -> DT/WMT writable
  for (int off=P1_DT+tid*16; off<P1_DT+16384; off+=4096) *(uint4*)(sm+off)=make_uint4(0,0,0,0);
  {
    int r=lane&15;
    const float* nb=(const float*)(sm+P1_NBD)+wave*256+r*16;
    float n[16], t_[16];
#pragma unroll
    for(int j=0;j<16;++j){ n[j]=nb[j]; t_[j]=(j==r)?1.f:0.f; }
#pragma unroll
    for(int s=0;s<15;++s){
      float tsj[16];
#pragma unroll
      for(int j=0;j<16;++j)
        tsj[j]=__int_as_float(__builtin_amdgcn_ds_bpermute(s*4,__float_as_int(t_[j])));
      if(r>s){
#pragma unroll
        for(int j=0;j<16;++j) t_[j]=fmaf(n[s],tsj[j],t_[j]);
      }
    }
    if(lane<16){
      u32 pk[8];
#pragma unroll
      for(int j=0;j<8;++j) pk[j]=packbf(t_[2*j],t_[2*j+1]);
      *(uint4*)(sm+aTII(wave,r,0)) =make_uint4(pk[0],pk[1],pk[2],pk[3]);
      *(uint4*)(sm+aTII(wave,r,16))=make_uint4(pk[4],pk[5],pk[6],pk[7]);
    }
  }
  __syncthreads();   // D
  {
    const float* WV=TB+128;
    int vb=16*wave;
    for(int i=0;i<4;++i){
      f32x4 acc;
#pragma unroll
      for(int p=0;p<4;++p) acc[p]=(vb+fr==16*i+fq*4+p)?1.f:0.f;
      int np=(i+1)>>1;
      for(int jp=0;jp<np;++jp){
        bf16x8 A=*(const bf16x8*)(sm+aNBP(16*i+fr,jp*64+fq*16));
        bf16x8 B=*(const bf16x8*)(sm+aDT(vb+fr,jp*64+fq*16));
        acc=mf(A,B,acc);
      }
      uint2 w1; w1.x=packbf(acc[0],acc[1]); w1.y=packbf(acc[2],acc[3]);
      *(uint2*)(sm+aR1T(vb+fr,fq*8))=w1;
      bf16x8 At=*(const bf16x8*)(sm+aTII(i,fr,fq*16));
      bf16x8 Bt=*(const bf16x8*)(sm+aR1T(vb+fr,fq*16));
      f32x4 dl=mf(At,Bt,z4);
      int s0=16*i+fq*4;
      uint2 wd; wd.x=packbf(dl[0],dl[1]); wd.y=packbf(dl[2],dl[3]);
      *(uint2*)(sm+aDT(vb+fr,s0*2))=wd;
      uint2 ww; ww.x=packbf(dl[0]*WV[s0],dl[1]*WV[s0+1]); ww.y=packbf(dl[2]*WV[s0+2],dl[3]*WV[s0+3]);
      *(uint2*)(sm+aWMT(vb+fr,s0*2))=ww;
    }
  }
  __syncthreads();   // E
  {
    u16* aout = aqmg + (size_t)b*4096;   // swizzled [64][64] for k_state LDS path
#pragma unroll
    for(int ts=0;ts<4;++ts){
      f32x4 acc=z4;
#pragma unroll
      for(int jp=0;jp<2;++jp){
        bf16x8 A=*(const bf16x8*)(sm+aAQ(16*wave+fr,jp*64+fq*16));
        bf16x8 B=*(const bf16x8*)(sm+aDT(16*ts+fr,jp*64+fq*16));
        acc=mf(A,B,acc);
      }
#pragma unroll
      for(int p=0;p<4;++p){
        int t=16*wave+fq*4+p, s=16*ts+fr;
        aout[(t*128 + ((s*2)^((t&7)<<4)))>>1]=f2bf(acc[p]);
      }
    }
    u16* kout = kwmg + (size_t)b*8192;   // swizzled [128][64]
#pragma unroll
    for(int j=0;j<2;++j){
      int dt=wave+4*j;
#pragma unroll
      for(int st=0;st<4;++st){
        f32x4 acc=z4;
#pragma unroll
        for(int jp=0;jp<2;++jp){
          bf16x8 A=*(const bf16x8*)(sm+aKT(16*dt+fr,jp*64+fq*16));
          bf16x8 B=*(const bf16x8*)(sm+aWMT(16*st+fr,jp*64+fq*16));
          acc=mf(A,B,acc);
        }
#pragma unroll
        for(int p=0;p<4;++p){
          int d=16*dt+fq*4+p, s=16*st+fr;
          kout[(d*128 + ((s*2)^((d&7)<<4)))>>1]=f2bf(acc[p]);
        }
      }
    }
  }
}

// ================ P2: sequential state pass (R14/R16/R19-proven LDS-staged) ================
#define P2_K(b)   ((b)*16384)
#define P2_Q(b)   (32768 + (b)*16384)
#define P2_W(b)   (65536 + (b)*16384)
#define P2_M(b)   (98304 + (b)*8192)
#define P2_TAB(b) (114688 + (b)*1024)
#define P2_ST(b)  (116736 + (b)*4096)
#define P2_R0T    124928
#define P2_SIZE   126976

#define bKx(b,r,cb)  (P2_K(b) + (r)*256 + SW7(r,cb))
#define bQx(b,r,cb)  (P2_Q(b) + (r)*256 + SW7(r,cb))
#define bWx(b,d,cb)  (P2_W(b) + (d)*128 + SW7(d,cb))
#define bMx(b,t,cb)  (P2_M(b) + (t)*128 + SW7(t,cb))
#define bSTx(b,v,cb) (P2_ST(b) + (v)*256 + SW7(v,cb))
#define bRx(v,cb)    (P2_R0T + (v)*128 + SW7(v,cb))

__global__ __launch_bounds__(256) void k_state(const u16* __restrict__ qn, const u16* __restrict__ kn,
    const u16* __restrict__ vv, const u16* __restrict__ aqmg, const u16* __restrict__ kwmg,
    const float* __restrict__ tabg, u16* __restrict__ ob){
  extern __shared__ char sm[];
  const int tid=threadIdx.x, lane=tid&63, wave=tid>>6;
  const int fr=lane&15, fq=lane>>4;
  const int h=blockIdx.x&31, vs=(blockIdx.x>>5)*16, kh=h>>1;
  const f32x4 z4={0.f,0.f,0.f,0.f};
  for(int off=116736+tid*16; off<124928; off+=4096) *(uint4*)(sm+off)=make_uint4(0,0,0,0);

  auto stage=[&](int c,int b){
    int srow=wave*4+(lane>>4);
    int pb2=(lane&15)*16;
#pragma unroll
    for(int r=0;r<4;++r){
      int row=r*16+srow;
      int gcb=pb2^((row&7)<<4);
      gld16((const char*)kn + ((size_t)((c<<6)+row)*KEY_DIM + kh*DKn)*2 + gcb, sm + P2_K(b)+r*4096+wave*1024);
      gld16((const char*)qn + ((size_t)((c<<6)+row)*KEY_DIM + kh*DKn)*2 + gcb, sm + P2_Q(b)+r*4096+wave*1024);
    }
    const char* wsrc=(const char*)kwmg + (size_t)(h*64+c)*16384;
#pragma unroll
    for(int r=0;r<4;++r)
      gld16(wsrc + r*4096 + wave*1024 + lane*16, sm + P2_W(b)+r*4096+wave*1024);
    const char* msrc=(const char*)aqmg + (size_t)(h*64+c)*8192;
#pragma unroll
    for(int r=0;r<2;++r)
      gld16(msrc + r*4096 + wave*1024 + lane*16, sm + P2_M(b)+r*4096+wave*1024);
    if(wave==0)
      gld16((const char*)tabg + (size_t)(h*64+c)*768 + lane*16, sm + P2_TAB(b));
  };
  u16 vl[4];
  auto loadV=[&](int c){
#pragma unroll
    for(int p=0;p<4;++p)
      vl[p]=vv[(size_t)((c<<6)+16*wave+fq*4+p)*VAL_DIM + h*DVn + vs + fr];
  };

  f32x4 S0=z4, S1=z4;
  stage(0,0); loadV(0);
  __syncthreads();

  for(int c=0;c<64;++c){
    int b=c&1;
    const float* TBf=(const float*)(sm+P2_TAB(b));
    f32x4 ks=z4;
#pragma unroll
    for(int kk=0;kk<4;++kk)
      ks=mf(*(const bf16x8*)(sm+bKx(b,16*wave+fr,kk*64+fq*16)),
            *(const bf16x8*)(sm+bSTx(b,fr,kk*64+fq*16)), ks);
    float r0v[4];
#pragma unroll
    for(int p=0;p<4;++p){
      int t=16*wave+fq*4+p;
      r0v[p]=TBf[64+t]*(bf2f(vl[p]) - TBf[t]*ks[p]);
    }
    uint2 rw; rw.x=packbf(r0v[0],r0v[1]); rw.y=packbf(r0v[2],r0v[3]);
    *(uint2*)(sm+bRx(fr,32*wave+8*fq))=rw;
    __syncthreads();
    if(c<63) stage(c+1,b^1);
    f32x4 qs=z4;
#pragma unroll
    for(int kk=0;kk<4;++kk)
      qs=mf(*(const bf16x8*)(sm+bQx(b,16*wave+fr,kk*64+fq*16)),
            *(const bf16x8*)(sm+bSTx(b,fr,kk*64+fq*16)), qs);
#pragma unroll
    for(int p=0;p<4;++p) qs[p]*=TBf[16*wave+fq*4+p];
#pragma unroll
    for(int jp=0;jp<2;++jp)
      qs=mf(*(const bf16x8*)(sm+bMx(b,16*wave+fr,jp*64+fq*16)),
            *(const bf16x8*)(sm+bRx(fr,jp*64+fq*16)), qs);
#pragma unroll
    for(int p=0;p<4;++p)
      ob[(size_t)((c<<6)+16*wave+fq*4+p)*VAL_DIM + h*DVn + vs + fr]=f2bf(qs[p]);
    if(c<63) loadV(c+1);
    float gl=TBf[128];
    S0[0]*=gl;S0[1]*=gl;S0[2]*=gl;S0[3]*=gl;
    S1[0]*=gl;S1[1]*=gl;S1[2]*=gl;S1[3]*=gl;
#pragma unroll
    for(int jp=0;jp<2;++jp){
      bf16x8 Br=*(const bf16x8*)(sm+bRx(fr,jp*64+fq*16));
      S0=mf(*(const bf16x8*)(sm+bWx(b,16*wave+fr,jp*64+fq*16)), Br, S0);
      S1=mf(*(const bf16x8*)(sm+bWx(b,16*(wave+4)+fr,jp*64+fq*16)), Br, S1);
    }
    uint2 s0w; s0w.x=packbf(S0[0],S0[1]); s0w.y=packbf(S0[2],S0[3]);
    *(uint2*)(sm+bSTx(b^1,fr,32*wave+8*fq))=s0w;
    uint2 s1w; s1w.x=packbf(S1[0],S1[1]); s1w.y=packbf(S1[2],S1[3]);
    *(uint2*)(sm+bSTx(b^1,fr,32*(wave+4)+8*fq))=s1w;
    __syncthreads();
  }
}

// ---------------- gated RMSNorm * silu(z) -> bf16 (bf16 input) ----------------
__global__ __launch_bounds__(256) void k_gnorm(const u16* __restrict__ ob, const u16* __restrict__ zq,
    const float* __restrict__ nw, u16* __restrict__ og){
  int t = blockIdx.x;
  int base = threadIdx.x*16;
  const u16* src = ob + (size_t)t*VAL_DIM + base;
  uint4 a0 = *(const uint4*)src;
  uint4 a1 = *(const uint4*)(src+8);
  u32 xr[8] = {a0.x,a0.y,a0.z,a0.w,a1.x,a1.y,a1.z,a1.w};
  float x[16];
#pragma unroll
  for (int p=0;p<8;++p){ x[2*p]=bf2f(xr[p]&0xffffu); x[2*p+1]=bf2f(xr[p]>>16); }
  float ss=0.f;
#pragma unroll
  for (int i=0;i<16;++i) ss += x[i]*x[i];
  ss += __shfl_xor(ss,1); ss += __shfl_xor(ss,2); ss += __shfl_xor(ss,4);
  float rs = 1.f/sqrtf(ss*(1.f/128.f) + 1e-6f);
  const u16* zp = zq + (size_t)t*VAL_DIM + base;
  uint4 z0 = *(const uint4*)zp;
  uint4 z1 = *(const uint4*)(zp+8);
  u32 zr[8] = {z0.x,z0.y,z0.z,z0.w,z1.x,z1.y,z1.z,z1.w};
  u32 outw[8];
#pragma unroll
  for (int p=0;p<8;++p){
    float za = bf2f(zr[p]&0xffffu), zb = bf2f(zr[p]>>16);
    float sa = za/(1.f+__expf(-za)), sb = zb/(1.f+__expf(-zb));
    int i0 = p*2, i1 = p*2+1;
    float oa = x[i0]*rs*nw[(base+i0)&127]*sa;
    float obv = x[i1]*rs*nw[(base+i1)&127]*sb;
    outw[p] = packbf(oa, obv);
  }
  uint4* dst = (uint4*)(og + (size_t)t*VAL_DIM + base);
  dst[0] = make_uint4(outw[0],outw[1],outw[2],outw[3]);
  dst[1] = make_uint4(outw[4],outw[5],outw[6],outw[7]);
}

extern "C" void kernel_launch(void* const* d_in, const int* in_sizes, int n_in,
                              void* d_out, int out_size, void* d_ws, size_t ws_size,
                              hipStream_t stream) {
  const float* hidden  = (const float*)d_in[0];
  const float* W_qkvz  = (const float*)d_in[1];
  const float* W_ba    = (const float*)d_in[2];
  const float* conv_w  = (const float*)d_in[3];
  const float* A_log   = (const float*)d_in[4];
  const float* dt_bias = (const float*)d_in[5];
  const float* norm_w  = (const float*)d_in[6];
  const float* W_out   = (const float*)d_in[7];

  char* w = (char*)d_ws;
  size_t need = 252706816;
  if (ws_size < need) return;

  u16*   Xb   = (u16*)(w + 0);
  u16*   W1T  = (u16*)(w + 16777216);
  u16*   QKV  = (u16*)(w + 67108864);
  u16*   Z    = (u16*)(w + 134217728);
  u16*   QN   = (u16*)(w + 167772160);
  u16*   KN   = (u16*)(w + 184549376);
  u16*   V    = (u16*)(w + 201326592);
  u16*   WoT  = (u16*)(w + 234881024);
  float* GTb  = (float*)(w + 251658240);
  float* BTb  = (float*)(w + 252182528);
  u16*   OB   = (u16*)(w + 0);
  u16*   AQMg = (u16*)(w + 67108864);
  u16*   KWMg = (u16*)(w + 83886080);
  float* TABg = (float*)(w + 117440512);
  u16*   OG   = (u16*)(w + 167772160);

  static int smem_set = 0;
  if (!smem_set){
    hipFuncSetAttribute((const void*)k_prep,  hipFuncAttributeMaxDynamicSharedMemorySize, P1_SIZE);
    hipFuncSetAttribute((const void*)k_state, hipFuncAttributeMaxDynamicSharedMemorySize, P2_SIZE);
    hipFuncSetAttribute((const void*)k_g256<1>, hipFuncAttributeMaxDynamicSharedMemorySize, G2_LDS);
    hipFuncSetAttribute((const void*)k_gw, hipFuncAttributeMaxDynamicSharedMemorySize, GW_LDS);
    smem_set = 1;
  }

  k_cvt<<<4096,256,0,stream>>>(hidden, Xb, T_LEN*H_DIM);
  k_tcvt<<<dim3(12288/32, H_DIM/32),256,0,stream>>>(W_qkvz, W1T, H_DIM, 12288);
  k_tcvt<<<dim3(H_DIM/32, VAL_DIM/32),256,0,stream>>>(W_out, WoT, VAL_DIM, H_DIM);
  k_ba<<<T_LEN/4,256,0,stream>>>(hidden, W_ba, A_log, dt_bias, GTb, BTb);
  k_g256<1><<<768,512,G2_LDS,stream>>>(Xb, W1T, QKV, Z, 8192, T_LEN, 12288, H_DIM);
  k_conv<<<dim3(128,4),256,0,stream>>>(QKV, conv_w, QN, KN, V);
  k_prep<<<2048,256,P1_SIZE,stream>>>(QN, KN, GTb, BTb, AQMg, KWMg, TABg);
  k_state<<<256,256,P2_SIZE,stream>>>(QN, KN, V, AQMg, KWMg, TABg, OB);
  k_gnorm<<<T_LEN,256,0,stream>>>(OB, Z, norm_w, OG);
  k_gw<<<256,512,GW_LDS,stream>>>(OG, WoT, (float*)d_out, T_LEN, H_DIM, VAL_DIM);
}